// Round 8
// baseline (688.173 us; speedup 1.0000x reference)
//
#include <hip/hip_runtime.h>
#include <math.h>

#define IN_F 64
#define HID 128
#define NCLS 10
#define H2S_STRIDE 16  // padded h2s row (64 B) -> one cache line per gather

// ---------- degree histogram over targets ----------
__global__ void k_hist(const int* __restrict__ col, int* __restrict__ cnt, int E) {
    int i = blockIdx.x * blockDim.x + threadIdx.x;
    if (i < E) atomicAdd(&cnt[col[i]], 1);
}

// ---------- 3-kernel exclusive scan (cnt -> rowptr) ----------
__global__ void k_blocksum(const int* __restrict__ cnt, int* __restrict__ bsum, int n) {
    __shared__ int s[256];
    int i = blockIdx.x * 256 + threadIdx.x;
    s[threadIdx.x] = (i < n) ? cnt[i] : 0;
    __syncthreads();
    for (int off = 128; off > 0; off >>= 1) {
        if (threadIdx.x < off) s[threadIdx.x] += s[threadIdx.x + off];
        __syncthreads();
    }
    if (threadIdx.x == 0) bsum[blockIdx.x] = s[0];
}

__global__ void k_scan_bsum(const int* __restrict__ bsum, int* __restrict__ boff, int nb,
                            int* __restrict__ rowptr, int n, int E) {
    __shared__ int s[512];
    int t = threadIdx.x;
    int v = (t < nb) ? bsum[t] : 0;
    s[t] = v;
    __syncthreads();
    for (int off = 1; off < 512; off <<= 1) {
        int tmp = (t >= off) ? s[t - off] : 0;
        __syncthreads();
        s[t] += tmp;
        __syncthreads();
    }
    if (t < nb) boff[t] = s[t] - v;  // exclusive
    if (t == 0) rowptr[n] = E;
}

// scan within block + write rowptr, pos (=rowptr copy), dis — fused
__global__ void k_scan_final(const int* __restrict__ cnt, const int* __restrict__ boff,
                             int* __restrict__ rowptr, int* __restrict__ pos,
                             float* __restrict__ dis, int n) {
    __shared__ int s[256];
    int i = blockIdx.x * 256 + threadIdx.x;
    int v = (i < n) ? cnt[i] : 0;
    s[threadIdx.x] = v;
    __syncthreads();
    for (int off = 1; off < 256; off <<= 1) {
        int tmp = (threadIdx.x >= off) ? s[threadIdx.x - off] : 0;
        __syncthreads();
        s[threadIdx.x] += tmp;
        __syncthreads();
    }
    if (i < n) {
        int rp = boff[blockIdx.x] + s[threadIdx.x] - v;  // exclusive
        rowptr[i] = rp;
        pos[i] = rp;
        dis[i] = rsqrtf(1.0f + (float)v);
    }
}

// ---------- CSR fill: src list sorted by target ----------
__global__ void k_fill(const int* __restrict__ row, const int* __restrict__ col,
                       int* __restrict__ pos, int* __restrict__ src, int E) {
    int e = blockIdx.x * blockDim.x + threadIdx.x;
    if (e >= E) return;
    int p = atomicAdd(&pos[col[e]], 1);
    src[p] = row[e];
}

// ---------- xs = x * dis[node] (fp32) ----------
__global__ void k_xs(const float* __restrict__ x, const float* __restrict__ dis,
                     float* __restrict__ xs, int n16) {
    int i = blockIdx.x * blockDim.x + threadIdx.x;
    if (i >= n16) return;
    float d = dis[i >> 4];  // 16 float4s per node (64 feats)
    float4 v = ((const float4*)x)[i];
    v.x *= d; v.y *= d; v.z *= d; v.w *= d;
    ((float4*)xs)[i] = v;
}

// ---------- XCD-sharded chunked gather: agg[i][64] = xs[i] + sum_src xs[src] ----------
// chunk = blockIdx.x & 7 -> lands on XCD (blockIdx%8); each XCD's gather working
// set is one 8-float chunk slice (3.2 MB) -> L2-resident.
// wave per node per chunk: 16 edge slots x 4 lanes x float2; x2 unroll.
__global__ __launch_bounds__(256) void k_gather(const float* __restrict__ xs,
                                                const int* __restrict__ src,
                                                const int* __restrict__ rowptr,
                                                float* __restrict__ agg, int n) {
    int chunk = blockIdx.x & 7;
    int nb = blockIdx.x >> 3;
    int w = threadIdx.x >> 6, lane = threadIdx.x & 63;
    int slot = lane >> 2;  // 0..15
    int f2 = lane & 3;     // float2 within the 8-float chunk
    int i = nb * 4 + w;
    if (i >= n) return;  // wave-uniform
    const float* base = xs + (size_t)chunk * 8 + (size_t)f2 * 2;
    float2 acc = make_float2(0.f, 0.f);
    if (slot == 0)  // self-loop term counted once
        acc = *(const float2*)(base + (size_t)i * IN_F);
    int beg = rowptr[i], end = rowptr[i + 1];
    int e = beg + slot;
    for (; e + 16 < end; e += 32) {
        int s0 = src[e];
        int s1 = src[e + 16];
        float2 v0 = *(const float2*)(base + (size_t)s0 * IN_F);
        float2 v1 = *(const float2*)(base + (size_t)s1 * IN_F);
        acc.x += v0.x + v1.x;
        acc.y += v0.y + v1.y;
    }
    if (e < end) {
        int s = src[e];
        float2 v = *(const float2*)(base + (size_t)s * IN_F);
        acc.x += v.x;
        acc.y += v.y;
    }
    // combine 16 slots: butterfly over lane bits 2..5
#pragma unroll
    for (int off = 4; off < 64; off <<= 1) {
        acc.x += __shfl_xor(acc.x, off, 64);
        acc.y += __shfl_xor(acc.y, off, 64);
    }
    if (slot == 0)
        ((float2*)(agg + (size_t)i * IN_F + chunk * 8))[f2] = acc;
}

// ---------- fused MLP: h2s[i] = dis*(relu(dis*agg @ W1 + b1) @ W2) ----------
// wave per node; GEMM1 via LDS broadcast (R3-proven epilogue); GEMM2 as
// parallel outer-product (20 FMA/lane) + 6-level butterfly reduce.
__global__ __launch_bounds__(256) void k_mlp(const float* __restrict__ agg,
                                             const float* __restrict__ dis,
                                             const float* __restrict__ W1,
                                             const float* __restrict__ b1,
                                             const float* __restrict__ W2,
                                             float* __restrict__ h2s, int n) {
    __shared__ float hacc[4][64];
    int w = threadIdx.x >> 6, lane = threadIdx.x & 63;
    int i = blockIdx.x * 4 + w;
    if (i >= n) return;  // wave-uniform
    float d = dis[i];
    if (lane < 16) {
        float4 v = ((const float4*)(agg + (size_t)i * IN_F))[lane];
        v.x *= d; v.y *= d; v.z *= d; v.w *= d;
        ((float4*)hacc[w])[lane] = v;
    }
    // wave-local LDS write->read: no block barrier needed (single wave)
    float h0 = b1[lane], h1 = b1[lane + 64];
#pragma unroll
    for (int k = 0; k < IN_F; ++k) {
        float a = hacc[w][k];  // LDS broadcast
        h0 = fmaf(a, W1[k * HID + lane], h0);
        h1 = fmaf(a, W1[k * HID + lane + 64], h1);
    }
    h0 = fmaxf(h0, 0.f);  // cols: lane, lane+64
    h1 = fmaxf(h1, 0.f);
    const float* w2a = W2 + lane * NCLS;
    const float* w2b = W2 + (lane + 64) * NCLS;
    float g[NCLS];
#pragma unroll
    for (int c = 0; c < NCLS; ++c) g[c] = fmaf(h0, w2a[c], h1 * w2b[c]);
#pragma unroll
    for (int off = 1; off < 64; off <<= 1) {
#pragma unroll
        for (int c = 0; c < NCLS; ++c) g[c] += __shfl_xor(g[c], off, 64);
    }
    if (lane == 0) {
        float* o = h2s + (size_t)i * H2S_STRIDE;
        *(float4*)(o) = make_float4(g[0] * d, g[1] * d, g[2] * d, g[3] * d);
        *(float4*)(o + 4) = make_float4(g[4] * d, g[5] * d, g[6] * d, g[7] * d);
        *(float2*)(o + 8) = make_float2(g[8] * d, g[9] * d);
    }
}

// ---------- fused gather2 + b2 + log-softmax + mean-reduce ----------
__global__ void k_lsm2(const float* __restrict__ h2s, const int* __restrict__ src,
                       const int* __restrict__ rowptr, const float* __restrict__ dis,
                       const float* __restrict__ b2, float* __restrict__ out, int n,
                       float inv_n) {
    __shared__ float sred[NCLS];
    if (threadIdx.x < NCLS) sred[threadIdx.x] = 0.f;
    __syncthreads();
    int i = blockIdx.x * blockDim.x + threadIdx.x;
    float loc[NCLS];
#pragma unroll
    for (int c = 0; c < NCLS; ++c) loc[c] = 0.f;
    if (i < n) {
        float a[NCLS], a2[NCLS];
        const float* self = h2s + (size_t)i * H2S_STRIDE;
        {
            float4 v0 = *(const float4*)(self);
            float4 v1 = *(const float4*)(self + 4);
            float2 v2 = *(const float2*)(self + 8);
            a[0] = v0.x; a[1] = v0.y; a[2] = v0.z; a[3] = v0.w;
            a[4] = v1.x; a[5] = v1.y; a[6] = v1.z; a[7] = v1.w;
            a[8] = v2.x; a[9] = v2.y;
#pragma unroll
            for (int c = 0; c < NCLS; ++c) a2[c] = 0.f;
        }
        int beg = rowptr[i], end = rowptr[i + 1];
        int e = beg;
        for (; e + 1 < end; e += 2) {  // 2 independent accumulator chains
            const float* p0 = h2s + (size_t)src[e] * H2S_STRIDE;
            const float* p1 = h2s + (size_t)src[e + 1] * H2S_STRIDE;
            float4 u0 = *(const float4*)(p0);
            float4 u1 = *(const float4*)(p0 + 4);
            float2 u2 = *(const float2*)(p0 + 8);
            float4 w0 = *(const float4*)(p1);
            float4 w1 = *(const float4*)(p1 + 4);
            float2 w2 = *(const float2*)(p1 + 8);
            a[0] += u0.x; a[1] += u0.y; a[2] += u0.z; a[3] += u0.w;
            a[4] += u1.x; a[5] += u1.y; a[6] += u1.z; a[7] += u1.w;
            a[8] += u2.x; a[9] += u2.y;
            a2[0] += w0.x; a2[1] += w0.y; a2[2] += w0.z; a2[3] += w0.w;
            a2[4] += w1.x; a2[5] += w1.y; a2[6] += w1.z; a2[7] += w1.w;
            a2[8] += w2.x; a2[9] += w2.y;
        }
        if (e < end) {
            const float* p = h2s + (size_t)src[e] * H2S_STRIDE;
            float4 u0 = *(const float4*)(p);
            float4 u1 = *(const float4*)(p + 4);
            float2 u2 = *(const float2*)(p + 8);
            a[0] += u0.x; a[1] += u0.y; a[2] += u0.z; a[3] += u0.w;
            a[4] += u1.x; a[5] += u1.y; a[6] += u1.z; a[7] += u1.w;
            a[8] += u2.x; a[9] += u2.y;
        }
        float d = dis[i];
        float vv[NCLS];
        float m = -1e30f;
#pragma unroll
        for (int c = 0; c < NCLS; ++c) {
            vv[c] = b2[c] + d * (a[c] + a2[c]);
            m = fmaxf(m, vv[c]);
        }
        float se = 0.f;
#pragma unroll
        for (int c = 0; c < NCLS; ++c) se += __expf(vv[c] - m);
        float lse = m + __logf(se);
#pragma unroll
        for (int c = 0; c < NCLS; ++c) loc[c] = vv[c] - lse;
    }
#pragma unroll
    for (int c = 0; c < NCLS; ++c) atomicAdd(&sred[c], loc[c]);
    __syncthreads();
    if (threadIdx.x < NCLS) atomicAdd(&out[threadIdx.x], sred[threadIdx.x] * inv_n);
}

extern "C" void kernel_launch(void* const* d_in, const int* in_sizes, int n_in,
                              void* d_out, int out_size, void* d_ws, size_t ws_size,
                              hipStream_t stream) {
    const float* x = (const float*)d_in[0];
    const int* eidx = (const int*)d_in[1];
    const float* W1 = (const float*)d_in[2];
    const float* b1 = (const float*)d_in[3];
    const float* W2 = (const float*)d_in[4];
    const float* b2 = (const float*)d_in[5];
    float* out = (float*)d_out;

    const int N = in_sizes[0] / IN_F;  // 100000
    const int E = in_sizes[1] / 2;     // 1600000
    const int* row = eidx;             // sources
    const int* col = eidx + E;         // targets

    const int NB = (N + 255) / 256;  // scan blocks (391 <= 512)

    // workspace layout (4-byte words, 1024-word aligned)
    size_t o = 0;
    auto alloc = [&](size_t words) {
        size_t r = o;
        o += (words + 1023) & ~(size_t)1023;
        return r;
    };
    float* ws = (float*)d_ws;
    float* dis = ws + alloc(N);
    float* xs = ws + alloc((size_t)N * IN_F);
    float* agg = ws + alloc((size_t)N * IN_F);
    float* h2s = ws + alloc((size_t)N * H2S_STRIDE);
    int* src = (int*)(ws + alloc(E));
    int* rowptr = (int*)(ws + alloc(N + 1));
    int* cnt = (int*)(ws + alloc(N));
    int* pos = (int*)(ws + alloc(N));
    int* bsum = (int*)(ws + alloc(1024));
    int* boff = (int*)(ws + alloc(1024));

    const int B = 256;

    // ---- CSR build + degrees ----
    hipMemsetAsync(cnt, 0, (size_t)N * sizeof(int), stream);
    k_hist<<<(E + B - 1) / B, B, 0, stream>>>(col, cnt, E);
    k_blocksum<<<NB, 256, 0, stream>>>(cnt, bsum, N);
    k_scan_bsum<<<1, 512, 0, stream>>>(bsum, boff, NB, rowptr, N, E);
    k_scan_final<<<NB, 256, 0, stream>>>(cnt, boff, rowptr, pos, dis, N);
    k_fill<<<(E + B - 1) / B, B, 0, stream>>>(row, col, pos, src, E);

    // ---- layer 1 aggregate (XCD-sharded chunks), then fused MLP ----
    k_xs<<<(N * 16 + B - 1) / B, B, 0, stream>>>(x, dis, xs, N * 16);
    {
        unsigned nblocks = (unsigned)(((N + 3) / 4) * 8);  // nodeblocks x 8 chunks
        k_gather<<<nblocks, 256, 0, stream>>>(xs, src, rowptr, agg, N);
    }
    k_mlp<<<(N + 3) / 4, 256, 0, stream>>>(agg, dis, W1, b1, W2, h2s, N);

    // ---- layer 2 aggregate + log-softmax + mean ----
    hipMemsetAsync(out, 0, NCLS * sizeof(float), stream);
    k_lsm2<<<NB, 256, 0, stream>>>(h2s, src, rowptr, dis, b2, out, N, 1.0f / (float)N);
}